// Round 3
// baseline (351.136 us; speedup 1.0000x reference)
//
#include <hip/hip_runtime.h>

#define GENE_N  200000
#define BATCH   200000
#define EMBED   128
#define BM      64
#define THREADS 512
#define LDS_STRIDE 136   // bf16 elems per LDS row: 128 + 8 pad
#define L2E     1.44269504088896340736f

typedef __attribute__((ext_vector_type(8))) short bf16x8;
typedef __attribute__((ext_vector_type(4))) float f32x4;

static __device__ __forceinline__ short f2bf(float f) {
    unsigned u = __builtin_bit_cast(unsigned, f);
    unsigned r = (u + 0x7fffu + ((u >> 16) & 1u)) >> 16;   // RNE
    return (short)(r & 0xffffu);
}
static __device__ __forceinline__ unsigned cvt_pk_bf16(float lo, float hi) {
    unsigned r;
    asm("v_cvt_pk_bf16_f32 %0, %1, %2" : "=v"(r) : "v"(lo), "v"(hi));
    return r;
}

__global__ __launch_bounds__(THREADS, 4)
void hetagg_kernel(const float* __restrict__ gene_feat,
                   const float* __restrict__ cell_feat,
                   const float* __restrict__ gWf, const float* __restrict__ gbf,
                   const float* __restrict__ gWb, const float* __restrict__ gbb,
                   const float* __restrict__ cWf, const float* __restrict__ cbf,
                   const float* __restrict__ cWb, const float* __restrict__ cbb,
                   const int* __restrict__ c_ids, const int* __restrict__ p_ids,
                   const int* __restrict__ n_ids, float* __restrict__ out,
                   int gene_blocks, int cell_blocks)
{
    __shared__ short A_lds[2][BM * LDS_STRIDE];

    const int  bid     = blockIdx.x;
    const bool is_gene = (bid < gene_blocks);
    const int  tid     = threadIdx.x;
    const int  wid     = tid >> 6;
    const int  lane    = tid & 63;
    const int  lgrp    = lane >> 4;   // 0..3
    const int  lcol    = lane & 15;   // 0..15
    const int  dir     = wid >> 2;    // 0 fwd, 1 bwd
    const int  jt      = wid & 3;     // 16-wide j block
    const int  j       = jt * 16 + lcol;

    const float* feat = is_gene ? gene_feat : cell_feat;
    const float* W    = is_gene ? (dir ? gWb : gWf) : (dir ? cWb : cWf);
    const float* Bv   = is_gene ? (dir ? gbb : gbf) : (dir ? cbb : cbf);

    // Gate scales fold exp()/exp2() conversion into the weights:
    //   a0 = -i*log2e   (u = 2^a0 = e^-i)
    //   a1 = 2g*log2e   (v = 2^a1 = e^{2g})
    //   a2 = -o*log2e   (w = 2^a2 = e^-o)
    const float gsc[3] = {-L2E, 2.0f * L2E, -L2E};
    // scaled biases, splatted into MFMA C-init
    const float b0 = -L2E * Bv[j];
    const float b1 = 2.0f * L2E * Bv[128 + j];
    const float b2 = -L2E * Bv[192 + j];
    const f32x4 binit[3] = {{b0, b0, b0, b0}, {b1, b1, b1, b1}, {b2, b2, b2, b2}};

    // B fragments in registers for the whole kernel (pre-scaled)
    bf16x8 bfrag[3][4];
    {
        const int gate_base[3] = {0, 128, 192};
#pragma unroll
        for (int q = 0; q < 3; ++q) {
            const float* wrow = W + (size_t)(gate_base[q] + j) * EMBED;
            const float  sc   = gsc[q];
#pragma unroll
            for (int s = 0; s < 4; ++s) {
                const int k0 = s * 32 + lgrp * 8;
                float4 w0 = *(const float4*)(wrow + k0);
                float4 w1 = *(const float4*)(wrow + k0 + 4);
                bf16x8 b;
                b[0] = f2bf(sc * w0.x); b[1] = f2bf(sc * w0.y);
                b[2] = f2bf(sc * w0.z); b[3] = f2bf(sc * w0.w);
                b[4] = f2bf(sc * w1.x); b[5] = f2bf(sc * w1.y);
                b[6] = f2bf(sc * w1.z); b[7] = f2bf(sc * w1.w);
                bfrag[q][s] = b;
            }
        }
    }

    const int myb    = is_gene ? bid : (bid - gene_blocks);
    const int nb     = is_gene ? gene_blocks : cell_blocks;
    const int ntiles = is_gene ? (BATCH / BM) : (2 * BATCH / BM);

    const int r0 = tid >> 5;   // 0..15
    const int cc = tid & 31;   // float4 col within row

#define FETCH_ID(grow) (is_gene ? c_ids[(grow)] \
                       : ((grow) < BATCH ? p_ids[(grow)] - GENE_N \
                                         : n_ids[(grow) - BATCH] - GENE_N))

    // ---- pipeline prologue ----
    int t = myb;
    float4 rv[4];   // prefetched rows of tile t
    int    idn[4];  // ids of tile t+nb
    {
        int id0[4];
#pragma unroll
        for (int p = 0; p < 4; ++p) id0[p] = FETCH_ID(t * BM + r0 + p * 16);
#pragma unroll
        for (int p = 0; p < 4; ++p)
            rv[p] = ((const float4*)(feat + (size_t)id0[p] * EMBED))[cc];
        const int t2 = t + nb;
#pragma unroll
        for (int p = 0; p < 4; ++p)
            idn[p] = (t2 < ntiles) ? FETCH_ID(t2 * BM + r0 + p * 16) : 0;
    }

    int pb = 0;   // LDS buffer parity
    for (; t < ntiles; t += nb, pb ^= 1) {
        const int  base = t * BM;
        const bool hn   = (t + nb < ntiles);
        short* buf = A_lds[pb];

        // ---- stage prefetched rows: cvt_pk f32->bf16 -> LDS ----
#pragma unroll
        for (int p = 0; p < 4; ++p) {
            int2 sv;
            sv.x = (int)cvt_pk_bf16(rv[p].x, rv[p].y);
            sv.y = (int)cvt_pk_bf16(rv[p].z, rv[p].w);
            *(int2*)&buf[(r0 + p * 16) * LDS_STRIDE + cc * 4] = sv;
        }
        asm volatile("s_waitcnt lgkmcnt(0)" ::: "memory");
        __builtin_amdgcn_s_barrier();
        // (single barrier per tile: double-buffered LDS makes the
        //  pre-stage barrier unnecessary — reads of buf[pb^1] from the
        //  previous iteration precede this barrier for every wave)

        // ---- issue next tile's gathers (fly during MFMA + epilogue) ----
        if (hn) {
#pragma unroll
            for (int p = 0; p < 4; ++p)
                rv[p] = ((const float4*)(feat + (size_t)idn[p] * EMBED))[cc];
            const int t3 = t + 2 * nb;
            if (t3 < ntiles) {
#pragma unroll
                for (int p = 0; p < 4; ++p)
                    idn[p] = FETCH_ID(t3 * BM + r0 + p * 16);
            }
        }

        // ---- MFMA (C initialized with scaled bias) ----
        f32x4 acc[4][3];
#pragma unroll
        for (int mt = 0; mt < 4; ++mt)
#pragma unroll
            for (int q = 0; q < 3; ++q)
                acc[mt][q] = binit[q];

#pragma unroll
        for (int s = 0; s < 4; ++s) {
#pragma unroll
            for (int mt = 0; mt < 4; ++mt) {
                const int m = mt * 16 + lcol;
                bf16x8 a = *(const bf16x8*)&buf[m * LDS_STRIDE + s * 32 + lgrp * 8];
                acc[mt][0] = __builtin_amdgcn_mfma_f32_16x16x32_bf16(a, bfrag[0][s], acc[mt][0], 0, 0, 0);
                acc[mt][1] = __builtin_amdgcn_mfma_f32_16x16x32_bf16(a, bfrag[1][s], acc[mt][1], 0, 0, 0);
                acc[mt][2] = __builtin_amdgcn_mfma_f32_16x16x32_bf16(a, bfrag[2][s], acc[mt][2], 0, 0, 0);
            }
        }

        // ---- epilogue: h = sigma(o)*tanh(sigma(i)*tanh(g)), exp2 domain ----
        // u=2^a0, v=2^a1, w=2^a2; c=(v-1)/((1+u)(v+1));
        // tanh(c) ~= c(15+c^2)/(15+6c^2); h = c(15+c^2)*rcp((15+6c^2)(1+w))
#pragma unroll
        for (int mt = 0; mt < 4; ++mt) {
#pragma unroll
            for (int r = 0; r < 4; ++r) {
                const float a0 = acc[mt][0][r];
                const float a1 = fminf(acc[mt][1][r], 80.0f);  // keep v finite
                const float a2 = acc[mt][2][r];
                const float u  = __builtin_amdgcn_exp2f(a0);
                const float v  = __builtin_amdgcn_exp2f(a1);
                const float w  = __builtin_amdgcn_exp2f(a2);
                const float tprod = (1.0f + u) * (v + 1.0f);
                const float c  = (v - 1.0f) * __builtin_amdgcn_rcpf(tprod);
                const float c2 = c * c;
                const float num = c * (15.0f + c2);
                const float den = (15.0f + 6.0f * c2) * (1.0f + w);
                const float h   = num * __builtin_amdgcn_rcpf(den);
                const int row   = base + mt * 16 + lgrp * 4 + r;
                const size_t orow = (size_t)(is_gene ? row : (BATCH + row));
                out[orow * 128 + dir * 64 + j] = h;
            }
        }
    }
#undef FETCH_ID
}

extern "C" void kernel_launch(void* const* d_in, const int* in_sizes, int n_in,
                              void* d_out, int out_size, void* d_ws, size_t ws_size,
                              hipStream_t stream)
{
    const float* gene_feat = (const float*)d_in[0];
    const float* cell_feat = (const float*)d_in[1];
    const float* gWf = (const float*)d_in[2];
    const float* gbf = (const float*)d_in[3];
    const float* gWb = (const float*)d_in[4];
    const float* gbb = (const float*)d_in[5];
    const float* cWf = (const float*)d_in[6];
    const float* cbf = (const float*)d_in[7];
    const float* cWb = (const float*)d_in[8];
    const float* cbb = (const float*)d_in[9];
    const int* c_ids = (const int*)d_in[10];
    const int* p_ids = (const int*)d_in[11];
    const int* n_ids = (const int*)d_in[12];
    float* out = (float*)d_out;

    const int gene_blocks = 171;   // 3125 tiles -> ~18.3 tiles/block
    const int cell_blocks = 341;   // 6250 tiles -> ~18.3 tiles/block
    dim3 grid(gene_blocks + cell_blocks);   // 512 blocks = 2/CU
    dim3 block(THREADS);
    hipLaunchKernelGGL(hetagg_kernel, grid, block, 0, stream,
                       gene_feat, cell_feat, gWf, gbf, gWb, gbb,
                       cWf, cbf, cWb, cbb, c_ids, p_ids, n_ids, out,
                       gene_blocks, cell_blocks);
}

// Round 4
// 184.220 us; speedup vs baseline: 1.9061x; 1.9061x over previous
//
#include <hip/hip_runtime.h>

#define GENE_N  200000
#define BATCH   200000
#define EMBED   128
#define BM      64
#define THREADS 512
#define LDS_STRIDE 136   // bf16 elems per LDS row: 128 + 8 pad
#define L2E     1.44269504088896340736f

typedef __attribute__((ext_vector_type(8))) short bf16x8;
typedef __attribute__((ext_vector_type(4))) float f32x4;

static __device__ __forceinline__ short f2bf(float f) {
    unsigned u = __builtin_bit_cast(unsigned, f);
    unsigned r = (u + 0x7fffu + ((u >> 16) & 1u)) >> 16;   // RNE
    return (short)(r & 0xffffu);
}
static __device__ __forceinline__ unsigned cvt_pk_bf16(float lo, float hi) {
    unsigned r;
    asm("v_cvt_pk_bf16_f32 %0, %1, %2" : "=v"(r) : "v"(lo), "v"(hi));
    return r;
}

__global__ __launch_bounds__(THREADS, 2)   // 256-reg cap: NO spill (r3 post-mortem: ",4" spilled bfrag/rv)
void hetagg_kernel(const float* __restrict__ gene_feat,
                   const float* __restrict__ cell_feat,
                   const float* __restrict__ gWf, const float* __restrict__ gbf,
                   const float* __restrict__ gWb, const float* __restrict__ gbb,
                   const float* __restrict__ cWf, const float* __restrict__ cbf,
                   const float* __restrict__ cWb, const float* __restrict__ cbb,
                   const int* __restrict__ c_ids, const int* __restrict__ p_ids,
                   const int* __restrict__ n_ids, float* __restrict__ out,
                   int gene_blocks, int cell_blocks)
{
    __shared__ short A_lds[2][BM * LDS_STRIDE];

    const int  bid     = blockIdx.x;
    const bool is_gene = (bid < gene_blocks);
    const int  tid     = threadIdx.x;
    const int  wid     = tid >> 6;
    const int  lane    = tid & 63;
    const int  lgrp    = lane >> 4;   // 0..3
    const int  lcol    = lane & 15;   // 0..15
    const int  dir     = wid >> 2;    // 0 fwd, 1 bwd
    const int  jt      = wid & 3;     // 16-wide j block
    const int  j       = jt * 16 + lcol;

    const float* feat = is_gene ? gene_feat : cell_feat;
    const float* W    = is_gene ? (dir ? gWb : gWf) : (dir ? cWb : cWf);
    const float* Bv   = is_gene ? (dir ? gbb : gbf) : (dir ? cbb : cbf);

    // exp2-domain gate scales folded into weights:
    //   a0 = -i*log2e (u=2^a0=e^-i); a1 = 2g*log2e (v=e^{2g}); a2 = -o*log2e (w=e^-o)
    const float gsc[3] = {-L2E, 2.0f * L2E, -L2E};
    const float b0 = -L2E * Bv[j];
    const float b1 = 2.0f * L2E * Bv[128 + j];
    const float b2 = -L2E * Bv[192 + j];
    const f32x4 binit[3] = {{b0, b0, b0, b0}, {b1, b1, b1, b1}, {b2, b2, b2, b2}};

    // B fragments in registers for the whole kernel (pre-scaled)
    bf16x8 bfrag[3][4];
    {
        const int gate_base[3] = {0, 128, 192};
#pragma unroll
        for (int q = 0; q < 3; ++q) {
            const float* wrow = W + (size_t)(gate_base[q] + j) * EMBED;
            const float  sc   = gsc[q];
#pragma unroll
            for (int s = 0; s < 4; ++s) {
                const int k0 = s * 32 + lgrp * 8;
                float4 w0 = *(const float4*)(wrow + k0);
                float4 w1 = *(const float4*)(wrow + k0 + 4);
                bf16x8 b;
                b[0] = f2bf(sc * w0.x); b[1] = f2bf(sc * w0.y);
                b[2] = f2bf(sc * w0.z); b[3] = f2bf(sc * w0.w);
                b[4] = f2bf(sc * w1.x); b[5] = f2bf(sc * w1.y);
                b[6] = f2bf(sc * w1.z); b[7] = f2bf(sc * w1.w);
                bfrag[q][s] = b;
            }
        }
    }

    const int myb    = is_gene ? bid : (bid - gene_blocks);
    const int nb     = is_gene ? gene_blocks : cell_blocks;
    const int ntiles = is_gene ? (BATCH / BM) : (2 * BATCH / BM);

    const int r0 = tid >> 5;   // 0..15
    const int cc = tid & 31;   // float4 col within row

#define FETCH_ID(grow) (is_gene ? c_ids[(grow)] \
                       : ((grow) < BATCH ? p_ids[(grow)] - GENE_N \
                                         : n_ids[(grow) - BATCH] - GENE_N))

    // ---- pipeline prologue ----
    int t = myb;
    float4 rv[4];   // prefetched rows of tile t
    int    idn[4];  // ids of tile t+nb
    {
        int id0[4];
#pragma unroll
        for (int p = 0; p < 4; ++p) id0[p] = FETCH_ID(t * BM + r0 + p * 16);
#pragma unroll
        for (int p = 0; p < 4; ++p)
            rv[p] = ((const float4*)(feat + (size_t)id0[p] * EMBED))[cc];
        const int t2 = t + nb;
#pragma unroll
        for (int p = 0; p < 4; ++p)
            idn[p] = (t2 < ntiles) ? FETCH_ID(t2 * BM + r0 + p * 16) : 0;
    }

    int pb = 0;   // LDS buffer parity
    for (; t < ntiles; t += nb, pb ^= 1) {
        const int  base = t * BM;
        const bool hn   = (t + nb < ntiles);
        short* buf = A_lds[pb];

        // ---- stage prefetched rows: cvt_pk f32->bf16 -> LDS ----
#pragma unroll
        for (int p = 0; p < 4; ++p) {
            int2 sv;
            sv.x = (int)cvt_pk_bf16(rv[p].x, rv[p].y);
            sv.y = (int)cvt_pk_bf16(rv[p].z, rv[p].w);
            *(int2*)&buf[(r0 + p * 16) * LDS_STRIDE + cc * 4] = sv;
        }
        asm volatile("s_waitcnt lgkmcnt(0)" ::: "memory");
        __builtin_amdgcn_s_barrier();
        // single barrier/tile: double-buffered LDS; previous tile's reads
        // precede this barrier in every wave's program order.

        // ---- issue next tile's gathers (fly during MFMA + epilogue) ----
        if (hn) {
#pragma unroll
            for (int p = 0; p < 4; ++p)
                rv[p] = ((const float4*)(feat + (size_t)idn[p] * EMBED))[cc];
            const int t3 = t + 2 * nb;
            if (t3 < ntiles) {
#pragma unroll
                for (int p = 0; p < 4; ++p)
                    idn[p] = FETCH_ID(t3 * BM + r0 + p * 16);
            }
        }

        // ---- MFMA (C initialized with scaled bias) ----
        f32x4 acc[4][3];
#pragma unroll
        for (int mt = 0; mt < 4; ++mt)
#pragma unroll
            for (int q = 0; q < 3; ++q)
                acc[mt][q] = binit[q];

#pragma unroll
        for (int s = 0; s < 4; ++s) {
#pragma unroll
            for (int mt = 0; mt < 4; ++mt) {
                const int m = mt * 16 + lcol;
                bf16x8 a = *(const bf16x8*)&buf[m * LDS_STRIDE + s * 32 + lgrp * 8];
                acc[mt][0] = __builtin_amdgcn_mfma_f32_16x16x32_bf16(a, bfrag[0][s], acc[mt][0], 0, 0, 0);
                acc[mt][1] = __builtin_amdgcn_mfma_f32_16x16x32_bf16(a, bfrag[1][s], acc[mt][1], 0, 0, 0);
                acc[mt][2] = __builtin_amdgcn_mfma_f32_16x16x32_bf16(a, bfrag[2][s], acc[mt][2], 0, 0, 0);
            }
        }

        // ---- epilogue: h = sigma(o)*tanh(sigma(i)*tanh(g)), exp2 domain ----
        // u=2^a0, v=2^a1, w=2^a2; c=(v-1)*rcp((1+u)(v+1));
        // tanh(c) ~= c(15+c^2)/(15+6c^2); h = c(15+c^2)*rcp((15+6c^2)(1+w))
#pragma unroll
        for (int mt = 0; mt < 4; ++mt) {
#pragma unroll
            for (int r = 0; r < 4; ++r) {
                const float a0 = acc[mt][0][r];
                const float a1 = fminf(acc[mt][1][r], 80.0f);  // keep v finite
                const float a2 = acc[mt][2][r];
                const float u  = __builtin_amdgcn_exp2f(a0);
                const float v  = __builtin_amdgcn_exp2f(a1);
                const float w  = __builtin_amdgcn_exp2f(a2);
                const float tprod = (1.0f + u) * (v + 1.0f);
                const float c  = (v - 1.0f) * __builtin_amdgcn_rcpf(tprod);
                const float c2 = c * c;
                const float num = c * (15.0f + c2);
                const float den = (15.0f + 6.0f * c2) * (1.0f + w);
                const float h   = num * __builtin_amdgcn_rcpf(den);
                const int row   = base + mt * 16 + lgrp * 4 + r;
                const size_t orow = (size_t)(is_gene ? row : (BATCH + row));
                out[orow * 128 + dir * 64 + j] = h;
            }
        }
    }
#undef FETCH_ID
}

extern "C" void kernel_launch(void* const* d_in, const int* in_sizes, int n_in,
                              void* d_out, int out_size, void* d_ws, size_t ws_size,
                              hipStream_t stream)
{
    const float* gene_feat = (const float*)d_in[0];
    const float* cell_feat = (const float*)d_in[1];
    const float* gWf = (const float*)d_in[2];
    const float* gbf = (const float*)d_in[3];
    const float* gWb = (const float*)d_in[4];
    const float* gbb = (const float*)d_in[5];
    const float* cWf = (const float*)d_in[6];
    const float* cbf = (const float*)d_in[7];
    const float* cWb = (const float*)d_in[8];
    const float* cbb = (const float*)d_in[9];
    const int* c_ids = (const int*)d_in[10];
    const int* p_ids = (const int*)d_in[11];
    const int* n_ids = (const int*)d_in[12];
    float* out = (float*)d_out;

    const int gene_blocks = 320;   // 3125 tiles -> ~9.8 tiles/block
    const int cell_blocks = 640;   // 6250 tiles -> ~9.8 tiles/block
    dim3 grid(gene_blocks + cell_blocks);
    dim3 block(THREADS);
    hipLaunchKernelGGL(hetagg_kernel, grid, block, 0, stream,
                       gene_feat, cell_feat, gWf, gbf, gWb, gbb,
                       cWf, cbf, cWb, cbb, c_ids, p_ids, n_ids, out,
                       gene_blocks, cell_blocks);
}

// Round 5
// 177.473 us; speedup vs baseline: 1.9785x; 1.0380x over previous
//
#include <hip/hip_runtime.h>

#define GENE_N  200000
#define BATCH   200000
#define EMBED   128
#define BM      64
#define THREADS 512
#define LDS_STRIDE 136   // bf16 elems per LDS row: 128 + 8 pad
#define L2E     1.44269504088896340736f

typedef __attribute__((ext_vector_type(8))) short bf16x8;
typedef __attribute__((ext_vector_type(4))) float f32x4;

static __device__ __forceinline__ short f2bf(float f) {
    unsigned u = __builtin_bit_cast(unsigned, f);
    unsigned r = (u + 0x7fffu + ((u >> 16) & 1u)) >> 16;   // RNE
    return (short)(r & 0xffffu);
}
static __device__ __forceinline__ unsigned cvt_pk_bf16(float lo, float hi) {
    unsigned r;
    asm("v_cvt_pk_bf16_f32 %0, %1, %2" : "=v"(r) : "v"(lo), "v"(hi));
    return r;
}

// (512,4): 128-reg cap -> 2 blocks/CU. Safe now: fused per-mt epilogue keeps
// only 3 accumulators (12 regs) live, demand ~100 unified regs (r4 had 132).
__global__ __launch_bounds__(THREADS, 4)
void hetagg_kernel(const float* __restrict__ gene_feat,
                   const float* __restrict__ cell_feat,
                   const float* __restrict__ gWf, const float* __restrict__ gbf,
                   const float* __restrict__ gWb, const float* __restrict__ gbb,
                   const float* __restrict__ cWf, const float* __restrict__ cbf,
                   const float* __restrict__ cWb, const float* __restrict__ cbb,
                   const int* __restrict__ c_ids, const int* __restrict__ p_ids,
                   const int* __restrict__ n_ids, float* __restrict__ out,
                   int gene_blocks, int cell_blocks)
{
    __shared__ short A_lds[2][BM * LDS_STRIDE];

    const int  bid     = blockIdx.x;
    const bool is_gene = (bid < gene_blocks);
    const int  tid     = threadIdx.x;
    const int  wid     = tid >> 6;
    const int  lane    = tid & 63;
    const int  lgrp    = lane >> 4;   // 0..3
    const int  lcol    = lane & 15;   // 0..15
    const int  dir     = wid >> 2;    // 0 fwd, 1 bwd
    const int  jt      = wid & 3;     // 16-wide j block
    const int  j       = jt * 16 + lcol;

    const float* feat = is_gene ? gene_feat : cell_feat;
    const float* W    = is_gene ? (dir ? gWb : gWf) : (dir ? cWb : cWf);
    const float* Bv   = is_gene ? (dir ? gbb : gbf) : (dir ? cbb : cbf);

    // exp2-domain gate scales folded into weights:
    //   a0 = -i*log2e (u=2^a0=e^-i); a1 = 2g*log2e (v=e^{2g}); a2 = -o*log2e (w=e^-o)
    const float gsc[3] = {-L2E, 2.0f * L2E, -L2E};
    const float b0 = -L2E * Bv[j];
    const float b1 = 2.0f * L2E * Bv[128 + j];
    const float b2 = -L2E * Bv[192 + j];

    // B fragments in registers for the whole kernel (pre-scaled)
    bf16x8 bfrag[3][4];
    {
        const int gate_base[3] = {0, 128, 192};
#pragma unroll
        for (int q = 0; q < 3; ++q) {
            const float* wrow = W + (size_t)(gate_base[q] + j) * EMBED;
            const float  sc   = gsc[q];
#pragma unroll
            for (int s = 0; s < 4; ++s) {
                const int k0 = s * 32 + lgrp * 8;
                float4 w0 = *(const float4*)(wrow + k0);
                float4 w1 = *(const float4*)(wrow + k0 + 4);
                bf16x8 b;
                b[0] = f2bf(sc * w0.x); b[1] = f2bf(sc * w0.y);
                b[2] = f2bf(sc * w0.z); b[3] = f2bf(sc * w0.w);
                b[4] = f2bf(sc * w1.x); b[5] = f2bf(sc * w1.y);
                b[6] = f2bf(sc * w1.z); b[7] = f2bf(sc * w1.w);
                bfrag[q][s] = b;
            }
        }
    }

    const int myb    = is_gene ? bid : (bid - gene_blocks);
    const int nb     = is_gene ? gene_blocks : cell_blocks;
    const int ntiles = is_gene ? (BATCH / BM) : (2 * BATCH / BM);

    const int r0 = tid >> 5;   // 0..15
    const int cc = tid & 31;   // float4 col within row

#define FETCH_ID(grow) (is_gene ? c_ids[(grow)] \
                       : ((grow) < BATCH ? p_ids[(grow)] - GENE_N \
                                         : n_ids[(grow) - BATCH] - GENE_N))

    // ---- pipeline prologue ----
    int t = myb;
    float4 rv[4];   // prefetched rows of tile t
    int    idn[4];  // ids of tile t+nb
    {
        int id0[4];
#pragma unroll
        for (int p = 0; p < 4; ++p) id0[p] = FETCH_ID(t * BM + r0 + p * 16);
#pragma unroll
        for (int p = 0; p < 4; ++p)
            rv[p] = ((const float4*)(feat + (size_t)id0[p] * EMBED))[cc];
        const int t2 = t + nb;
#pragma unroll
        for (int p = 0; p < 4; ++p)
            idn[p] = (t2 < ntiles) ? FETCH_ID(t2 * BM + r0 + p * 16) : 0;
    }

    int pb = 0;   // LDS buffer parity
    for (; t < ntiles; t += nb, pb ^= 1) {
        const int  base = t * BM;
        const bool hn   = (t + nb < ntiles);
        short* buf = A_lds[pb];

        // ---- stage prefetched rows: cvt_pk f32->bf16 -> LDS ----
#pragma unroll
        for (int p = 0; p < 4; ++p) {
            int2 sv;
            sv.x = (int)cvt_pk_bf16(rv[p].x, rv[p].y);
            sv.y = (int)cvt_pk_bf16(rv[p].z, rv[p].w);
            *(int2*)&buf[(r0 + p * 16) * LDS_STRIDE + cc * 4] = sv;
        }
        asm volatile("s_waitcnt lgkmcnt(0)" ::: "memory");
        __builtin_amdgcn_s_barrier();
        // single barrier/tile: double-buffered LDS; previous tile's reads
        // precede this barrier in every wave's program order.

        // ---- issue next tile's gathers (fly during MFMA + epilogue) ----
        if (hn) {
#pragma unroll
            for (int p = 0; p < 4; ++p)
                rv[p] = ((const float4*)(feat + (size_t)idn[p] * EMBED))[cc];
            const int t3 = t + 2 * nb;
            if (t3 < ntiles) {
#pragma unroll
                for (int p = 0; p < 4; ++p)
                    idn[p] = FETCH_ID(t3 * BM + r0 + p * 16);
            }
        }

        // ---- MFMA + fused epilogue, one 16-row slab (mt) at a time ----
        // Only 3 accumulators (12 regs) live at once (r4 had 48 AGPR live
        // -> 132 unified regs -> 1 block/CU).
#pragma unroll
        for (int mt = 0; mt < 4; ++mt) {
            f32x4 acc0 = {b0, b0, b0, b0};
            f32x4 acc1 = {b1, b1, b1, b1};
            f32x4 acc2 = {b2, b2, b2, b2};
            const int m = mt * 16 + lcol;
#pragma unroll
            for (int s = 0; s < 4; ++s) {
                bf16x8 a = *(const bf16x8*)&buf[m * LDS_STRIDE + s * 32 + lgrp * 8];
                acc0 = __builtin_amdgcn_mfma_f32_16x16x32_bf16(a, bfrag[0][s], acc0, 0, 0, 0);
                acc1 = __builtin_amdgcn_mfma_f32_16x16x32_bf16(a, bfrag[1][s], acc1, 0, 0, 0);
                acc2 = __builtin_amdgcn_mfma_f32_16x16x32_bf16(a, bfrag[2][s], acc2, 0, 0, 0);
            }
            // epilogue: h = sigma(o)*tanh(sigma(i)*tanh(g)), exp2 domain
            // u=2^a0, v=2^a1, w=2^a2; c=(v-1)*rcp((1+u)(v+1));
            // tanh(c) ~= c(15+c^2)/(15+6c^2); h = c(15+c^2)*rcp((15+6c^2)(1+w))
#pragma unroll
            for (int r = 0; r < 4; ++r) {
                const float a0 = acc0[r];
                const float a1 = fminf(acc1[r], 80.0f);  // keep v finite
                const float a2 = acc2[r];
                const float u  = __builtin_amdgcn_exp2f(a0);
                const float v  = __builtin_amdgcn_exp2f(a1);
                const float w  = __builtin_amdgcn_exp2f(a2);
                const float tprod = (1.0f + u) * (v + 1.0f);
                const float c  = (v - 1.0f) * __builtin_amdgcn_rcpf(tprod);
                const float c2 = c * c;
                const float num = c * (15.0f + c2);
                const float den = (15.0f + 6.0f * c2) * (1.0f + w);
                const float h   = num * __builtin_amdgcn_rcpf(den);
                const int row   = base + mt * 16 + lgrp * 4 + r;
                const size_t orow = (size_t)(is_gene ? row : (BATCH + row));
                out[orow * 128 + dir * 64 + j] = h;
            }
        }
    }
#undef FETCH_ID
}

extern "C" void kernel_launch(void* const* d_in, const int* in_sizes, int n_in,
                              void* d_out, int out_size, void* d_ws, size_t ws_size,
                              hipStream_t stream)
{
    const float* gene_feat = (const float*)d_in[0];
    const float* cell_feat = (const float*)d_in[1];
    const float* gWf = (const float*)d_in[2];
    const float* gbf = (const float*)d_in[3];
    const float* gWb = (const float*)d_in[4];
    const float* gbb = (const float*)d_in[5];
    const float* cWf = (const float*)d_in[6];
    const float* cbf = (const float*)d_in[7];
    const float* cWb = (const float*)d_in[8];
    const float* cbb = (const float*)d_in[9];
    const int* c_ids = (const int*)d_in[10];
    const int* p_ids = (const int*)d_in[11];
    const int* n_ids = (const int*)d_in[12];
    float* out = (float*)d_out;

    const int gene_blocks = 341;   // 3125 tiles -> ~9.2 tiles/block
    const int cell_blocks = 683;   // 6250 tiles -> ~9.2 tiles/block
    dim3 grid(gene_blocks + cell_blocks);   // 1024 = 2 blocks/CU x 2 rounds
    dim3 block(THREADS);
    hipLaunchKernelGGL(hetagg_kernel, grid, block, 0, stream,
                       gene_feat, cell_feat, gWf, gbf, gWb, gbb,
                       cWf, cbf, cWb, cbb, c_ids, p_ids, n_ids, out,
                       gene_blocks, cell_blocks);
}

// Round 6
// 153.746 us; speedup vs baseline: 2.2839x; 1.1543x over previous
//
#include <hip/hip_runtime.h>

#define GENE_N  200000
#define BATCH   200000
#define EMBED   128
#define BM      32
#define THREADS 512
#define LDS_STRIDE 136   // bf16 elems per LDS row: 128 + 8 pad
#define L2E     1.44269504088896340736f

typedef __attribute__((ext_vector_type(8))) short bf16x8;
typedef __attribute__((ext_vector_type(4))) float f32x4;

static __device__ __forceinline__ short f2bf(float f) {
    unsigned u = __builtin_bit_cast(unsigned, f);
    unsigned r = (u + 0x7fffu + ((u >> 16) & 1u)) >> 16;   // RNE
    return (short)(r & 0xffffu);
}
static __device__ __forceinline__ unsigned cvt_pk_bf16(float lo, float hi) {
    unsigned r;
    asm("v_cvt_pk_bf16_f32 %0, %1, %2" : "=v"(r) : "v"(lo), "v"(hi));
    return r;
}

// (512,4) = 2 blocks/CU (128-reg cap). BM=32 shrinks per-thread pipeline
// state so arch-side demand ~50 regs, AGPR side (bfrag 48 + acc 12) = 60:
// both under the 64/64 split -> no spill (r5 spilled at BM=64 + depth-1).
__global__ __launch_bounds__(THREADS, 4)
void hetagg_kernel(const float* __restrict__ gene_feat,
                   const float* __restrict__ cell_feat,
                   const float* __restrict__ gWf, const float* __restrict__ gbf,
                   const float* __restrict__ gWb, const float* __restrict__ gbb,
                   const float* __restrict__ cWf, const float* __restrict__ cbf,
                   const float* __restrict__ cWb, const float* __restrict__ cbb,
                   const int* __restrict__ c_ids, const int* __restrict__ p_ids,
                   const int* __restrict__ n_ids, float* __restrict__ out,
                   int gene_blocks, int cell_blocks)
{
    __shared__ short A_lds[2][BM * LDS_STRIDE];

    const int  bid     = blockIdx.x;
    const bool is_gene = (bid < gene_blocks);
    const int  tid     = threadIdx.x;
    const int  wid     = tid >> 6;
    const int  lane    = tid & 63;
    const int  lgrp    = lane >> 4;   // 0..3
    const int  lcol    = lane & 15;   // 0..15
    const int  dir     = wid >> 2;    // 0 fwd, 1 bwd
    const int  jt      = wid & 3;     // 16-wide j block
    const int  j       = jt * 16 + lcol;

    const float* feat = is_gene ? gene_feat : cell_feat;
    const float* W    = is_gene ? (dir ? gWb : gWf) : (dir ? cWb : cWf);
    const float* Bv   = is_gene ? (dir ? gbb : gbf) : (dir ? cbb : cbf);

    // exp2-domain gate scales folded into weights:
    //   a0 = -i*log2e (u=2^a0=e^-i); a1 = 2g*log2e (v=e^{2g}); a2 = -o*log2e (w=e^-o)
    const float gsc[3] = {-L2E, 2.0f * L2E, -L2E};
    const float b0 = -L2E * Bv[j];
    const float b1 = 2.0f * L2E * Bv[128 + j];
    const float b2 = -L2E * Bv[192 + j];

    // B fragments in registers (AGPR-side) for the whole kernel (pre-scaled)
    bf16x8 bfrag[3][4];
    {
        const int gate_base[3] = {0, 128, 192};
#pragma unroll
        for (int q = 0; q < 3; ++q) {
            const float* wrow = W + (size_t)(gate_base[q] + j) * EMBED;
            const float  sc   = gsc[q];
#pragma unroll
            for (int s = 0; s < 4; ++s) {
                const int k0 = s * 32 + lgrp * 8;
                float4 w0 = *(const float4*)(wrow + k0);
                float4 w1 = *(const float4*)(wrow + k0 + 4);
                bf16x8 b;
                b[0] = f2bf(sc * w0.x); b[1] = f2bf(sc * w0.y);
                b[2] = f2bf(sc * w0.z); b[3] = f2bf(sc * w0.w);
                b[4] = f2bf(sc * w1.x); b[5] = f2bf(sc * w1.y);
                b[6] = f2bf(sc * w1.z); b[7] = f2bf(sc * w1.w);
                bfrag[q][s] = b;
            }
        }
    }

    const int myb    = is_gene ? bid : (bid - gene_blocks);
    const int nb     = is_gene ? gene_blocks : cell_blocks;
    const int ntiles = is_gene ? (BATCH / BM) : (2 * BATCH / BM);
    const int nk     = (ntiles - myb + nb - 1) / nb;   // tiles for this block

    const int r0 = tid >> 5;   // 0..15 (row within half-pass)
    const int cc = tid & 31;   // float4 col within row

#define FETCH_ID(grow) (is_gene ? c_ids[(grow)] \
                       : ((grow) < BATCH ? p_ids[(grow)] - GENE_N \
                                         : n_ids[(grow) - BATCH] - GENE_N))

    // ---- depth-2 pipeline prologue: rows(0)->rvA, rows(1)->rvB, ids(2)->idC
    float4 rvA[2], rvB[2];
    int    idC[2];
    {
        int id0[2], id1[2];
        const int ta = myb * BM;
#pragma unroll
        for (int p = 0; p < 2; ++p) id0[p] = FETCH_ID(ta + r0 + p * 16);
#pragma unroll
        for (int p = 0; p < 2; ++p)
            rvA[p] = ((const float4*)(feat + (size_t)id0[p] * EMBED))[cc];
        if (nk > 1) {
            const int tb = (myb + nb) * BM;
#pragma unroll
            for (int p = 0; p < 2; ++p) id1[p] = FETCH_ID(tb + r0 + p * 16);
#pragma unroll
            for (int p = 0; p < 2; ++p)
                rvB[p] = ((const float4*)(feat + (size_t)id1[p] * EMBED))[cc];
        }
        if (nk > 2) {
            const int tc = (myb + 2 * nb) * BM;
#pragma unroll
            for (int p = 0; p < 2; ++p) idC[p] = FETCH_ID(tc + r0 + p * 16);
        }
    }

    int pb = 0;   // LDS buffer parity

    // Tile body: stage RV -> barrier -> prefetch(k+2 into RV, ids k+3) ->
    // MFMA + fused epilogue. Static register banks via macro (rule #20).
#define TILE_BODY(K, RV)                                                        \
    {                                                                           \
        const int t_    = myb + (K) * nb;                                       \
        const int base_ = t_ * BM;                                              \
        short* buf = A_lds[pb];                                                 \
        _Pragma("unroll")                                                       \
        for (int p = 0; p < 2; ++p) {                                           \
            int2 sv;                                                            \
            sv.x = (int)cvt_pk_bf16(RV[p].x, RV[p].y);                          \
            sv.y = (int)cvt_pk_bf16(RV[p].z, RV[p].w);                          \
            *(int2*)&buf[(r0 + p * 16) * LDS_STRIDE + cc * 4] = sv;             \
        }                                                                       \
        asm volatile("s_waitcnt lgkmcnt(0)" ::: "memory");                      \
        __builtin_amdgcn_s_barrier();                                           \
        if ((K) + 2 < nk) {                                                     \
            _Pragma("unroll")                                                   \
            for (int p = 0; p < 2; ++p)                                         \
                RV[p] = ((const float4*)(feat + (size_t)idC[p] * EMBED))[cc];   \
        }                                                                       \
        if ((K) + 3 < nk) {                                                     \
            const int tn_ = (myb + ((K) + 3) * nb) * BM;                        \
            _Pragma("unroll")                                                   \
            for (int p = 0; p < 2; ++p) idC[p] = FETCH_ID(tn_ + r0 + p * 16);   \
        }                                                                       \
        _Pragma("unroll")                                                       \
        for (int mt = 0; mt < 2; ++mt) {                                        \
            f32x4 acc0 = {b0, b0, b0, b0};                                      \
            f32x4 acc1 = {b1, b1, b1, b1};                                      \
            f32x4 acc2 = {b2, b2, b2, b2};                                      \
            const int m_ = mt * 16 + lcol;                                      \
            _Pragma("unroll")                                                   \
            for (int s = 0; s < 4; ++s) {                                       \
                bf16x8 a = *(const bf16x8*)&buf[m_ * LDS_STRIDE + s * 32 + lgrp * 8]; \
                acc0 = __builtin_amdgcn_mfma_f32_16x16x32_bf16(a, bfrag[0][s], acc0, 0, 0, 0); \
                acc1 = __builtin_amdgcn_mfma_f32_16x16x32_bf16(a, bfrag[1][s], acc1, 0, 0, 0); \
                acc2 = __builtin_amdgcn_mfma_f32_16x16x32_bf16(a, bfrag[2][s], acc2, 0, 0, 0); \
            }                                                                   \
            _Pragma("unroll")                                                   \
            for (int r = 0; r < 4; ++r) {                                       \
                const float a0 = acc0[r];                                       \
                const float a1 = fminf(acc1[r], 80.0f);                         \
                const float a2 = acc2[r];                                       \
                const float u  = __builtin_amdgcn_exp2f(a0);                    \
                const float v  = __builtin_amdgcn_exp2f(a1);                    \
                const float w  = __builtin_amdgcn_exp2f(a2);                    \
                const float tprod = (1.0f + u) * (v + 1.0f);                    \
                const float c  = (v - 1.0f) * __builtin_amdgcn_rcpf(tprod);     \
                const float c2 = c * c;                                         \
                const float num = c * (15.0f + c2);                             \
                const float den = (15.0f + 6.0f * c2) * (1.0f + w);             \
                const float h   = num * __builtin_amdgcn_rcpf(den);             \
                const int row   = base_ + mt * 16 + lgrp * 4 + r;               \
                const size_t orow = (size_t)(is_gene ? row : (BATCH + row));    \
                out[orow * 128 + dir * 64 + j] = h;                             \
            }                                                                   \
        }                                                                       \
        pb ^= 1;                                                                \
    }

    int k = 0;
    for (; k + 1 < nk; k += 2) {
        TILE_BODY(k, rvA);
        TILE_BODY(k + 1, rvB);
    }
    if (k < nk) TILE_BODY(k, rvA);

#undef TILE_BODY
#undef FETCH_ID
}

extern "C" void kernel_launch(void* const* d_in, const int* in_sizes, int n_in,
                              void* d_out, int out_size, void* d_ws, size_t ws_size,
                              hipStream_t stream)
{
    const float* gene_feat = (const float*)d_in[0];
    const float* cell_feat = (const float*)d_in[1];
    const float* gWf = (const float*)d_in[2];
    const float* gbf = (const float*)d_in[3];
    const float* gWb = (const float*)d_in[4];
    const float* gbb = (const float*)d_in[5];
    const float* cWf = (const float*)d_in[6];
    const float* cbf = (const float*)d_in[7];
    const float* cWb = (const float*)d_in[8];
    const float* cbb = (const float*)d_in[9];
    const int* c_ids = (const int*)d_in[10];
    const int* p_ids = (const int*)d_in[11];
    const int* n_ids = (const int*)d_in[12];
    float* out = (float*)d_out;

    const int gene_blocks = 171;   // 6250 tiles of 32 rows -> 36-37 tiles/block
    const int cell_blocks = 341;   // 12500 tiles           -> 36-37 tiles/block
    dim3 grid(gene_blocks + cell_blocks);   // 512 = 2 blocks/CU, one round
    dim3 block(THREADS);
    hipLaunchKernelGGL(hetagg_kernel, grid, block, 0, stream,
                       gene_feat, cell_feat, gWf, gbf, gWb, gbb,
                       cWf, cbf, cWb, cbb, c_ids, p_ids, n_ids, out,
                       gene_blocks, cell_blocks);
}